// Round 6
// baseline (1632.985 us; speedup 1.0000x reference)
//
#include <hip/hip_runtime.h>
#include <cstdint>

#define T_STEPS 128
#define BATCH   1024
#define D_INPUT 96
#define H_DIM   128
#define NWIN    163   // 121 full 7-frame windows + 6 prefix partials + 36 clipped partials

// window table: widx -> (start frame, length)
__device__ __forceinline__ void win_decode(int widx, int& start, int& len) {
    if (widx < 121)      { start = widx;        len = 7; }            // [w, w+6]
    else if (widx < 127) { start = 0;           len = widx - 120; }   // s=0 grow, len 1..6
    else { const int r = widx - 127; const int s = 1 + r / 6;
           len = 1 + r % 6;          start = 7 * s - 1; }             // s>=1 grow partials
}

// (t, s) -> widx, or -1 when the reference window is empty (cur1 == +0)
__device__ __forceinline__ int widx_for(int t, int s) {
    if (t >= 49) return t - 49 + 7 * s;                 // slide regime: full windows
    if (s == 0)  return 121 + min(5, t);                // [0, min(5,t)]
    const int st = 7 * s - 1;
    if (t < st) return -1;
    const int len = min(7, t - st + 1);
    return (len == 7) ? st : (127 + (s - 1) * 6 + (len - 1));
}

// ---------------------------------------------------------------------------
// kA: CUR1[widx][b][h] = seqFMA_{d}( wsum[d], Win[h][d] ) — bit-identical to
// round 3 (ascending-k frame adds, ascending-d single-acc fmaf). Cooperative:
// block = 16 b x 128 h; window sums staged in LDS; 4 b per Win fetch.
// (unchanged from round 5 for clean attribution; ~245 us, next target)
// ---------------------------------------------------------------------------
__global__ __launch_bounds__(256) void kA_wincur(const float* __restrict__ x,
                                                 const float* __restrict__ Win,
                                                 float* __restrict__ CUR1) {
    __shared__ float xs[D_INPUT * 16];                  // xs[d*16 + bq], 6 KB
    const int widx = blockIdx.x;
    const int b0   = blockIdx.y * 16;
    int start, len; win_decode(widx, start, len);
    const int tid = threadIdx.x;

    for (int e = tid; e < D_INPUT * 16; e += 256) {
        const int d = e % D_INPUT, bq = e / D_INPUT;
        const float* xp = x + ((size_t)start * BATCH + b0 + bq) * D_INPUT + d;
        float s = xp[0];
        for (int k = 1; k < len; ++k)                   // ascending frame order (exact)
            s = __fadd_rn(s, xp[(size_t)k * BATCH * D_INPUT]);
        xs[d * 16 + bq] = s;
    }
    __syncthreads();

    const int hp = tid & 63, g = tid >> 6;              // h-pair, b-quad (g uniform/wave)
    const int h0 = hp << 1;
    const float* w0 = Win + (size_t)h0 * D_INPUT;
    const float* w1 = w0 + D_INPUT;
    float a00=0.f,a01=0.f,a10=0.f,a11=0.f,a20=0.f,a21=0.f,a30=0.f,a31=0.f;
#pragma unroll 8
    for (int d = 0; d < D_INPUT; ++d) {                 // ascending d, one acc each (exact)
        const float4 xv = *(const float4*)&xs[d * 16 + g * 4];   // LDS broadcast
        const float f0 = w0[d], f1 = w1[d];
        a00 = __fmaf_rn(xv.x, f0, a00); a01 = __fmaf_rn(xv.x, f1, a01);
        a10 = __fmaf_rn(xv.y, f0, a10); a11 = __fmaf_rn(xv.y, f1, a11);
        a20 = __fmaf_rn(xv.z, f0, a20); a21 = __fmaf_rn(xv.z, f1, a21);
        a30 = __fmaf_rn(xv.w, f0, a30); a31 = __fmaf_rn(xv.w, f1, a31);
    }
    float* op = CUR1 + ((size_t)widx * BATCH + b0 + g * 4) * H_DIM + h0;
    float2 o;
    o.x = a00; o.y = a01; *(float2*)(op            ) = o;
    o.x = a10; o.y = a11; *(float2*)(op +     H_DIM) = o;
    o.x = a20; o.y = a21; *(float2*)(op + 2 * H_DIM) = o;
    o.x = a30; o.y = a31; *(float2*)(op + 3 * H_DIM) = o;
}

// ---------------------------------------------------------------------------
// kB: 7 SNN steps, EIGHT (t,b) pairs per wave (amortizes each ds_read_b64
// over 8 pairs; fma total invariant), 8 waves/block sharing the 64 KB W_h0
// table. XOR-swizzled rows: lw_idx(h,i) = h*128 + (i ^ 2(h&63)) — float2
// pairs stay 8B-aligned; init writes ~4-way instead of 64-way conflicted.
// cur2 = dense ascending-h fma chain with {0.0f,1.0f} spike floats built
// from the wave-uniform ballot mask halves on the SCALAR pipe — bit-exact
// to sgemm's conditional fmaf chain. __launch_bounds__(512,4): VGPR cap 128
// (spill guard; round 4's (1024,4)=64-cap caused 50 GB scratch traffic).
// Linear tail (W_out / mem_out) relaxed: per-lane Horner + butterfly reduce.
// ---------------------------------------------------------------------------
__device__ __forceinline__ int lw_idx(int h, int i) {
    return (h << 7) | (i ^ ((h & 63) << 1));
}

__global__ __launch_bounds__(512, 4) void kB_snn(const float* __restrict__ CUR1,
                                                 const float* __restrict__ Wh0,
                                                 const float* __restrict__ Wout,
                                                 const float* __restrict__ vxp,
                                                 const float* __restrict__ vyp,
                                                 float* __restrict__ out) {
    __shared__ float lw[H_DIM * H_DIM];                 // 64 KB
    const int tid = threadIdx.x;
    for (int e = tid; e < H_DIM * H_DIM; e += 512) {
        const int i = e >> 7, h = e & 127;              // Wh0 flat = i*128 + h
        lw[lw_idx(h, i)] = Wh0[e];                      // coalesced read, cheap write
    }
    __syncthreads();

    const int w = tid >> 6, lane = tid & 63;
    const int t  = blockIdx.y;
    const int i0 = lane << 1;
    const float wex = Wout[i0],     wey = Wout[H_DIM + i0];
    const float wox = Wout[i0 + 1], woy = Wout[H_DIM + i0 + 1];
    const float vx = vxp[0], vy = vyp[0];
    const int b0 = (blockIdx.x << 6) + (w << 3);        // 8 consecutive b per wave

    float m1a[8], m1b[8], m2a[8], m2b[8], poa[8], pob[8];
    bool  s1a[8], s1b[8], s2a[8], s2b[8];
#pragma unroll
    for (int k = 0; k < 8; ++k) {
        m1a[k]=0.f; m1b[k]=0.f; m2a[k]=0.f; m2b[k]=0.f; poa[k]=0.f; pob[k]=0.f;
        s1a[k]=false; s1b[k]=false; s2a[k]=false; s2b[k]=false;
    }

#pragma unroll 1
    for (int s = 0; s < 7; ++s) {
        // ---- load cur1, mem1 update, ballots (exact) -----------------------
        const int wi = widx_for(t, s);                  // wave-uniform
        uint32_t meL[8], meH[8], moL[8], moH[8];        // mask halves (SGPRs)
#pragma unroll
        for (int k = 0; k < 8; ++k) {
            float ca = 0.f, cb = 0.f;
            if (wi >= 0) {
                const float2 v = *(const float2*)
                    &CUR1[((size_t)wi * BATCH + b0 + k) * H_DIM + i0];
                ca = v.x; cb = v.y;
            }
            m1a[k] = s1a[k] ? 0.f : __fadd_rn(__fmul_rn(0.9f, m1a[k]), ca);
            m1b[k] = s1b[k] ? 0.f : __fadd_rn(__fmul_rn(0.9f, m1b[k]), cb);
            s1a[k] = m1a[k] > 0.5f; s1b[k] = m1b[k] > 0.5f;
            const uint64_t me = __ballot(s1a[k]);       // bit l -> h = 2l
            const uint64_t mo = __ballot(s1b[k]);       // bit l -> h = 2l+1
            meL[k] = (uint32_t)me; meH[k] = (uint32_t)(me >> 32);
            moL[k] = (uint32_t)mo; moH[k] = (uint32_t)(mo >> 32);
        }

        // ---- dense cur2: ascending h, fma with {0,1} spike floats (exact) ---
        float c2a[8] = {0,0,0,0,0,0,0,0}, c2b[8] = {0,0,0,0,0,0,0,0};
#pragma unroll 16
        for (int j = 0; j < 64; ++j) {
            const float2 we = *(const float2*)&lw[lw_idx(2*j,     i0)];
            const float2 wo = *(const float2*)&lw[lw_idx(2*j + 1, i0)];
#pragma unroll
            for (int k = 0; k < 8; ++k) {
                // j is a compile-time constant here -> scalar s_bfe + s_cselect
                const uint32_t be = ((j < 32 ? meL[k] >> j : meH[k] >> (j - 32)) & 1u);
                const uint32_t bo = ((j < 32 ? moL[k] >> j : moH[k] >> (j - 32)) & 1u);
                const float se = __uint_as_float(be ? 0x3f800000u : 0u);
                const float so = __uint_as_float(bo ? 0x3f800000u : 0u);
                c2a[k] = __fmaf_rn(se, we.x, c2a[k]);   // h = 2j
                c2b[k] = __fmaf_rn(se, we.y, c2b[k]);
                c2a[k] = __fmaf_rn(so, wo.x, c2a[k]);   // h = 2j+1
                c2b[k] = __fmaf_rn(so, wo.y, c2b[k]);
            }
        }

        // ---- mem2 + spikes (exact) and linear output tail (relaxed) ---------
#pragma unroll
        for (int k = 0; k < 8; ++k) {
            m2a[k] = s2a[k] ? 0.f : __fadd_rn(__fmul_rn(0.9f, m2a[k]), c2a[k]);
            m2b[k] = s2b[k] ? 0.f : __fadd_rn(__fmul_rn(0.9f, m2b[k]), c2b[k]);
            s2a[k] = m2a[k] > 0.5f; s2b[k] = m2b[k] > 0.5f;
            const float p0 = (s2a[k] ? wex : 0.f) + (s2b[k] ? wox : 0.f);
            const float p1 = (s2a[k] ? wey : 0.f) + (s2b[k] ? woy : 0.f);
            poa[k] = __fmaf_rn(0.9f, poa[k], p0);       // mem_out is linear: order-safe
            pob[k] = __fmaf_rn(0.9f, pob[k], p1);
        }
    }

    // ---- reduce per-lane output partials, write -----------------------------
#pragma unroll
    for (int k = 0; k < 8; ++k) {
        float r0 = poa[k], r1 = pob[k];
#pragma unroll
        for (int off = 32; off > 0; off >>= 1) {
            r0 += __shfl_xor(r0, off);
            r1 += __shfl_xor(r1, off);
        }
        if (lane == 0) {
            float2 o;
            o.x = __fmul_rn(r0, vx);
            o.y = __fmul_rn(r1, vy);
            *(float2*)(out + ((size_t)t * BATCH + b0 + k) * 2) = o;
        }
    }
}

// ---------------------------------------------------------------------------
extern "C" void kernel_launch(void* const* d_in, const int* in_sizes, int n_in,
                              void* d_out, int out_size, void* d_ws, size_t ws_size,
                              hipStream_t stream) {
    const float* x    = (const float*)d_in[0];   // (128,1024,96)
    const float* Win  = (const float*)d_in[1];   // (128,96)
    const float* Wh0  = (const float*)d_in[2];   // (128,128)
    const float* Wout = (const float*)d_in[3];   // (2,128)
    const float* vx   = (const float*)d_in[4];   // (1,)
    const float* vy   = (const float*)d_in[5];   // (1,)
    float* out  = (float*)d_out;                 // (128,1024,2)
    float* CUR1 = (float*)d_ws;                  // 163*1024*128*4 = 85.5 MB

    kA_wincur<<<dim3(NWIN, BATCH / 16),   dim3(256), 0, stream>>>(x, Win, CUR1);
    kB_snn   <<<dim3(BATCH / 64, T_STEPS), dim3(512), 0, stream>>>(CUR1, Wh0, Wout, vx, vy, out);
}

// Round 7
// 958.604 us; speedup vs baseline: 1.7035x; 1.7035x over previous
//
#include <hip/hip_runtime.h>
#include <cstdint>

#define T_STEPS 128
#define BATCH   1024
#define D_INPUT 96
#define H_DIM   128
#define NWIN    163   // 121 full 7-frame windows + 6 prefix partials + 36 clipped partials

// window table: widx -> (start frame, length)
__device__ __forceinline__ void win_decode(int widx, int& start, int& len) {
    if (widx < 121)      { start = widx;        len = 7; }            // [w, w+6]
    else if (widx < 127) { start = 0;           len = widx - 120; }   // s=0 grow, len 1..6
    else { const int r = widx - 127; const int s = 1 + r / 6;
           len = 1 + r % 6;          start = 7 * s - 1; }             // s>=1 grow partials
}

// (t, s) -> widx, or -1 when the reference window is empty (cur1 == +0)
__device__ __forceinline__ int widx_for(int t, int s) {
    if (t >= 49) return t - 49 + 7 * s;                 // slide regime: full windows
    if (s == 0)  return 121 + min(5, t);                // [0, min(5,t)]
    const int st = 7 * s - 1;
    if (t < st) return -1;
    const int len = min(7, t - st + 1);
    return (len == 7) ? st : (127 + (s - 1) * 6 + (len - 1));
}

// XOR swizzle keeping even/odd float2 pairs adjacent and 8B-aligned
__device__ __forceinline__ int swz_idx(int row, int col) {
    return (row << 7) | (col ^ ((row & 63) << 1));
}

// ---------------------------------------------------------------------------
// kA: CUR1[widx][b][h] = seqFMA_{d}( wsum[d], Win[h][d] ) — bit-identical
// arithmetic (ascending-k frame adds, ascending-d single-acc fmaf). Round 6
// post-mortem: Win reads were per-lane stride-384B UNCOALESCED global loads
// (h0 is lane-dependent) — now Win is staged transposed in LDS (XOR-swizzled
// so the (h0,h0+1) float2 stays adjacent): per d = 1 ds_read_b64 +
// 1 broadcast ds_read_b128 + 8 fma.
// ---------------------------------------------------------------------------
__global__ __launch_bounds__(256) void kA_wincur(const float* __restrict__ x,
                                                 const float* __restrict__ Win,
                                                 float* __restrict__ CUR1) {
    __shared__ float xs[D_INPUT * 16];                  // xs[d*16 + bq], 6 KB
    __shared__ float wT[D_INPUT * H_DIM];               // 48 KB, wT[swz_idx(d,h)]
    const int widx = blockIdx.x;
    const int b0   = blockIdx.y * 16;
    int start, len; win_decode(widx, start, len);
    const int tid = threadIdx.x;

    // stage Win transposed (coalesced read, one-time scattered LDS write)
    for (int e = tid; e < H_DIM * D_INPUT; e += 256) {
        const int h = e / D_INPUT, d = e % D_INPUT;     // Win flat = h*96 + d
        wT[swz_idx(d, h)] = Win[e];
    }
    // window sums (exact ascending-frame adds)
    for (int e = tid; e < D_INPUT * 16; e += 256) {
        const int d = e % D_INPUT, bq = e / D_INPUT;
        const float* xp = x + ((size_t)start * BATCH + b0 + bq) * D_INPUT + d;
        float s = xp[0];
        for (int k = 1; k < len; ++k)
            s = __fadd_rn(s, xp[(size_t)k * BATCH * D_INPUT]);
        xs[d * 16 + bq] = s;
    }
    __syncthreads();

    const int hp = tid & 63, g = tid >> 6;              // h-pair, b-quad (g uniform/wave)
    const int h0 = hp << 1;
    float a00=0.f,a01=0.f,a10=0.f,a11=0.f,a20=0.f,a21=0.f,a30=0.f,a31=0.f;
#pragma unroll 8
    for (int d = 0; d < D_INPUT; ++d) {                 // ascending d, one acc each (exact)
        const float2 wp = *(const float2*)&wT[swz_idx(d, h0)];   // ds_read_b64
        const float4 xv = *(const float4*)&xs[d * 16 + g * 4];   // broadcast b128
        a00 = __fmaf_rn(xv.x, wp.x, a00); a01 = __fmaf_rn(xv.x, wp.y, a01);
        a10 = __fmaf_rn(xv.y, wp.x, a10); a11 = __fmaf_rn(xv.y, wp.y, a11);
        a20 = __fmaf_rn(xv.z, wp.x, a20); a21 = __fmaf_rn(xv.z, wp.y, a21);
        a30 = __fmaf_rn(xv.w, wp.x, a30); a31 = __fmaf_rn(xv.w, wp.y, a31);
    }
    float* op = CUR1 + ((size_t)widx * BATCH + b0 + g * 4) * H_DIM + h0;
    float2 o;
    o.x = a00; o.y = a01; *(float2*)(op            ) = o;
    o.x = a10; o.y = a11; *(float2*)(op +     H_DIM) = o;
    o.x = a20; o.y = a21; *(float2*)(op + 2 * H_DIM) = o;
    o.x = a30; o.y = a31; *(float2*)(op + 3 * H_DIM) = o;
}

// ---------------------------------------------------------------------------
// kB: 7 SNN steps, 8 (t,b) pairs per wave, 8 waves/block sharing the 64 KB
// swizzled W_h0 table. Round 6 post-mortem: per-element mask bit-extracts
// compiled to the shared SALU -> issue-starved (VALUBusy 22%). Now spike
// {0.0f,1.0f} floats are built per-lane ONCE per step (v_cndmask), written
// to a wave-private LDS strip sf[j][0..15] (4x ds_write_b128), and the
// j-loop reads them with uniform-address broadcast ds_read_b128 — no
// ballots, no SALU, ~84% pure-fma issue density. Bit-exact: identical
// {0,1} values, same ascending-h single-accumulator fma chain.
// LDS 96 KB -> 1 block/CU; next-step cur1 register prefetch re-added.
// __launch_bounds__(512,2): VGPR cap 256 (spill guard, round-4 lesson).
// ---------------------------------------------------------------------------
__global__ __launch_bounds__(512, 2) void kB_snn(const float* __restrict__ CUR1,
                                                 const float* __restrict__ Wh0,
                                                 const float* __restrict__ Wout,
                                                 const float* __restrict__ vxp,
                                                 const float* __restrict__ vyp,
                                                 float* __restrict__ out) {
    __shared__ float lw[H_DIM * H_DIM];                 // 64 KB, lw[swz_idx(h,i)]
    __shared__ float sf[8][64 * 16];                    // 32 KB, per-wave spike floats
    const int tid = threadIdx.x;
    for (int e = tid; e < H_DIM * H_DIM; e += 512) {
        const int i = e >> 7, h = e & 127;              // Wh0 flat = i*128 + h
        lw[swz_idx(h, i)] = Wh0[e];
    }
    __syncthreads();

    const int w = tid >> 6, lane = tid & 63;
    const int t  = blockIdx.y;
    const int i0 = lane << 1;
    float* sfw = sf[w];
    const float wex = Wout[i0],     wey = Wout[H_DIM + i0];
    const float wox = Wout[i0 + 1], woy = Wout[H_DIM + i0 + 1];
    const float vx = vxp[0], vy = vyp[0];
    const int b0 = (blockIdx.x << 6) + (w << 3);        // 8 consecutive b per wave

    float m1a[8], m1b[8], m2a[8], m2b[8], poa[8], pob[8];
    float c1a[8], c1b[8];
    bool  s1a[8], s1b[8], s2a[8], s2b[8];
#pragma unroll
    for (int k = 0; k < 8; ++k) {
        m1a[k]=0.f; m1b[k]=0.f; m2a[k]=0.f; m2b[k]=0.f; poa[k]=0.f; pob[k]=0.f;
        s1a[k]=false; s1b[k]=false; s2a[k]=false; s2b[k]=false;
    }

    // prefetch cur1 for s = 0
    {
        const int wi = widx_for(t, 0);
#pragma unroll
        for (int k = 0; k < 8; ++k) {
            c1a[k] = 0.f; c1b[k] = 0.f;
            if (wi >= 0) {
                const float2 v = *(const float2*)
                    &CUR1[((size_t)wi * BATCH + b0 + k) * H_DIM + i0];
                c1a[k] = v.x; c1b[k] = v.y;
            }
        }
    }

#pragma unroll 1
    for (int s = 0; s < 7; ++s) {
        // ---- prefetch next step's cur1 into registers (covered by j-loop) --
        float n1a[8], n1b[8];
        const int win = (s < 6) ? widx_for(t, s + 1) : -1;
#pragma unroll
        for (int k = 0; k < 8; ++k) {
            n1a[k] = 0.f; n1b[k] = 0.f;
            if (win >= 0) {
                const float2 v = *(const float2*)
                    &CUR1[((size_t)win * BATCH + b0 + k) * H_DIM + i0];
                n1a[k] = v.x; n1b[k] = v.y;
            }
        }

        // ---- mem1 update + spike floats (exact) ----------------------------
        float sev[8], sov[8];
#pragma unroll
        for (int k = 0; k < 8; ++k) {
            m1a[k] = s1a[k] ? 0.f : __fadd_rn(__fmul_rn(0.9f, m1a[k]), c1a[k]);
            m1b[k] = s1b[k] ? 0.f : __fadd_rn(__fmul_rn(0.9f, m1b[k]), c1b[k]);
            s1a[k] = m1a[k] > 0.5f; s1b[k] = m1b[k] > 0.5f;
            sev[k] = s1a[k] ? 1.0f : 0.0f;              // v_cndmask, once per step
            sov[k] = s1b[k] ? 1.0f : 0.0f;
        }
        // publish this lane's source-pair spikes: sfw[lane*16 + 0..7]=se, 8..15=so
        {
            float4 v;
            v.x=sev[0]; v.y=sev[1]; v.z=sev[2]; v.w=sev[3]; *(float4*)&sfw[lane*16     ] = v;
            v.x=sev[4]; v.y=sev[5]; v.z=sev[6]; v.w=sev[7]; *(float4*)&sfw[lane*16 +  4] = v;
            v.x=sov[0]; v.y=sov[1]; v.z=sov[2]; v.w=sov[3]; *(float4*)&sfw[lane*16 +  8] = v;
            v.x=sov[4]; v.y=sov[5]; v.z=sov[6]; v.w=sov[7]; *(float4*)&sfw[lane*16 + 12] = v;
        }
        // wave-lockstep: all 64 lanes' writes precede any read after lgkmcnt

        // ---- dense cur2: ascending h, fma with broadcast spike floats ------
        float c2a[8] = {0,0,0,0,0,0,0,0}, c2b[8] = {0,0,0,0,0,0,0,0};
#pragma unroll 8
        for (int j = 0; j < 64; ++j) {
            const float2 we = *(const float2*)&lw[swz_idx(2*j,     i0)]; // per-lane b64
            const float2 wo = *(const float2*)&lw[swz_idx(2*j + 1, i0)];
            const float4 e03 = *(const float4*)&sfw[j*16     ];          // broadcast b128
            const float4 e47 = *(const float4*)&sfw[j*16 +  4];
            const float4 o03 = *(const float4*)&sfw[j*16 +  8];
            const float4 o47 = *(const float4*)&sfw[j*16 + 12];
            const float se[8] = {e03.x,e03.y,e03.z,e03.w, e47.x,e47.y,e47.z,e47.w};
            const float so[8] = {o03.x,o03.y,o03.z,o03.w, o47.x,o47.y,o47.z,o47.w};
#pragma unroll
            for (int k = 0; k < 8; ++k) {
                c2a[k] = __fmaf_rn(se[k], we.x, c2a[k]);   // h = 2j
                c2b[k] = __fmaf_rn(se[k], we.y, c2b[k]);
                c2a[k] = __fmaf_rn(so[k], wo.x, c2a[k]);   // h = 2j+1
                c2b[k] = __fmaf_rn(so[k], wo.y, c2b[k]);
            }
        }

        // ---- mem2 + spikes (exact) and linear output tail (relaxed) --------
#pragma unroll
        for (int k = 0; k < 8; ++k) {
            m2a[k] = s2a[k] ? 0.f : __fadd_rn(__fmul_rn(0.9f, m2a[k]), c2a[k]);
            m2b[k] = s2b[k] ? 0.f : __fadd_rn(__fmul_rn(0.9f, m2b[k]), c2b[k]);
            s2a[k] = m2a[k] > 0.5f; s2b[k] = m2b[k] > 0.5f;
            const float p0 = (s2a[k] ? wex : 0.f) + (s2b[k] ? wox : 0.f);
            const float p1 = (s2a[k] ? wey : 0.f) + (s2b[k] ? woy : 0.f);
            poa[k] = __fmaf_rn(0.9f, poa[k], p0);       // mem_out is linear: order-safe
            pob[k] = __fmaf_rn(0.9f, pob[k], p1);
            c1a[k] = n1a[k]; c1b[k] = n1b[k];
        }
    }

    // ---- reduce per-lane output partials, write -----------------------------
#pragma unroll
    for (int k = 0; k < 8; ++k) {
        float r0 = poa[k], r1 = pob[k];
#pragma unroll
        for (int off = 32; off > 0; off >>= 1) {
            r0 += __shfl_xor(r0, off);
            r1 += __shfl_xor(r1, off);
        }
        if (lane == 0) {
            float2 o;
            o.x = __fmul_rn(r0, vx);
            o.y = __fmul_rn(r1, vy);
            *(float2*)(out + ((size_t)t * BATCH + b0 + k) * 2) = o;
        }
    }
}

// ---------------------------------------------------------------------------
extern "C" void kernel_launch(void* const* d_in, const int* in_sizes, int n_in,
                              void* d_out, int out_size, void* d_ws, size_t ws_size,
                              hipStream_t stream) {
    const float* x    = (const float*)d_in[0];   // (128,1024,96)
    const float* Win  = (const float*)d_in[1];   // (128,96)
    const float* Wh0  = (const float*)d_in[2];   // (128,128)
    const float* Wout = (const float*)d_in[3];   // (2,128)
    const float* vx   = (const float*)d_in[4];   // (1,)
    const float* vy   = (const float*)d_in[5];   // (1,)
    float* out  = (float*)d_out;                 // (128,1024,2)
    float* CUR1 = (float*)d_ws;                  // 163*1024*128*4 = 85.5 MB

    kA_wincur<<<dim3(NWIN, BATCH / 16),   dim3(256), 0, stream>>>(x, Win, CUR1);
    kB_snn   <<<dim3(BATCH / 64, T_STEPS), dim3(512), 0, stream>>>(CUR1, Wh0, Wout, vx, vy, out);
}

// Round 8
// 898.037 us; speedup vs baseline: 1.8184x; 1.0674x over previous
//
#include <hip/hip_runtime.h>
#include <cstdint>

#define T_STEPS 128
#define BATCH   1024
#define D_INPUT 96
#define H_DIM   128
#define NWIN    163   // 121 full 7-frame windows + 6 prefix partials + 36 clipped partials

// window table: widx -> (start frame, length)
__device__ __forceinline__ void win_decode(int widx, int& start, int& len) {
    if (widx < 121)      { start = widx;        len = 7; }            // [w, w+6]
    else if (widx < 127) { start = 0;           len = widx - 120; }   // s=0 grow, len 1..6
    else { const int r = widx - 127; const int s = 1 + r / 6;
           len = 1 + r % 6;          start = 7 * s - 1; }             // s>=1 grow partials
}

// (t, s) -> widx, or -1 when the reference window is empty (cur1 == +0)
__device__ __forceinline__ int widx_for(int t, int s) {
    if (t >= 49) return t - 49 + 7 * s;                 // slide regime: full windows
    if (s == 0)  return 121 + min(5, t);                // [0, min(5,t)]
    const int st = 7 * s - 1;
    if (t < st) return -1;
    const int len = min(7, t - st + 1);
    return (len == 7) ? st : (127 + (s - 1) * 6 + (len - 1));
}

// XOR swizzle keeping even/odd float2 pairs adjacent and 8B-aligned
__device__ __forceinline__ int swz_idx(int row, int col) {
    return (row << 7) | (col ^ ((row & 63) << 1));
}

// ---------------------------------------------------------------------------
// kA: CUR1[widx][b][h] = seqFMA_{d}( wsum[d], Win[h][d] ) — bit-identical
// arithmetic (ascending-k frame adds, ascending-d single-acc fmaf).
// Round 8: b-tile 32 (halves wT staging per output; per-d LDS 30cyc < fma
// 32cyc), 60 KB LDS -> 2 blocks/CU. Wave g handles b-octet g*8..g*8+7.
// ---------------------------------------------------------------------------
__global__ __launch_bounds__(256) void kA_wincur(const float* __restrict__ x,
                                                 const float* __restrict__ Win,
                                                 float* __restrict__ CUR1) {
    __shared__ float xs[D_INPUT * 32];                  // xs[d*32 + bq], 12 KB
    __shared__ float wT[D_INPUT * H_DIM];               // 48 KB, wT[swz_idx(d,h)]
    const int widx = blockIdx.x;
    const int b0   = blockIdx.y * 32;
    int start, len; win_decode(widx, start, len);
    const int tid = threadIdx.x;

    // stage Win transposed (coalesced read, one-time scattered LDS write)
    for (int e = tid; e < H_DIM * D_INPUT; e += 256) {
        const int h = e / D_INPUT, d = e % D_INPUT;     // Win flat = h*96 + d
        wT[swz_idx(d, h)] = Win[e];
    }
    // window sums (exact ascending-frame adds); coalesced global reads
    for (int e = tid; e < D_INPUT * 32; e += 256) {
        const int d = e % D_INPUT, bq = e / D_INPUT;
        const float* xp = x + ((size_t)start * BATCH + b0 + bq) * D_INPUT + d;
        float s = xp[0];
        for (int k = 1; k < len; ++k)
            s = __fadd_rn(s, xp[(size_t)k * BATCH * D_INPUT]);
        xs[d * 32 + bq] = s;
    }
    __syncthreads();

    const int hp = tid & 63, g = tid >> 6;              // h-pair; wave -> b-octet
    const int h0 = hp << 1;
    float acc[8][2];
#pragma unroll
    for (int r = 0; r < 8; ++r) { acc[r][0] = 0.f; acc[r][1] = 0.f; }

#pragma unroll 6
    for (int d = 0; d < D_INPUT; ++d) {                 // ascending d, one acc each (exact)
        const float2 wp  = *(const float2*)&wT[swz_idx(d, h0)];      // ds_read_b64
        const float4 xv0 = *(const float4*)&xs[d * 32 + g * 8];      // broadcast b128
        const float4 xv1 = *(const float4*)&xs[d * 32 + g * 8 + 4];
        const float xv[8] = {xv0.x,xv0.y,xv0.z,xv0.w, xv1.x,xv1.y,xv1.z,xv1.w};
#pragma unroll
        for (int r = 0; r < 8; ++r) {
            acc[r][0] = __fmaf_rn(xv[r], wp.x, acc[r][0]);
            acc[r][1] = __fmaf_rn(xv[r], wp.y, acc[r][1]);
        }
    }
    float* op = CUR1 + ((size_t)widx * BATCH + b0 + g * 8) * H_DIM + h0;
#pragma unroll
    for (int r = 0; r < 8; ++r) {
        float2 o; o.x = acc[r][0]; o.y = acc[r][1];
        *(float2*)(op + (size_t)r * H_DIM) = o;
    }
}

// ---------------------------------------------------------------------------
// kB: 7 SNN steps, SIXTEEN (t,b) pairs per wave (per j: 2 b64 + 8 broadcast
// b128 ≈ 52 LDS-cyc vs 64 fma = 128 VALU-cyc — VALU-dominant, ILP hides LDS
// latency at 2 waves/SIMD). 8 waves/block share the 64 KB swizzled W_h0
// table; per-wave 8 KB sf strip publishes spike {0,1} floats with chunk
// swizzle c^(lane&7) (round 7's writes were 16/32-way bank-conflicted).
// cur1 prefetch for s+1 reuses the dead c1 registers. Bit-exact: same {0,1}
// values, same ascending-h single-accumulator fma chain; membranes
// rn(rn(0.9*m)+c) with select-0 reset. Linear W_out/mem_out tail relaxed.
// __launch_bounds__(512,2): VGPR cap 256 (spill guard, round-4 lesson).
// ---------------------------------------------------------------------------
__global__ __launch_bounds__(512, 2) void kB_snn(const float* __restrict__ CUR1,
                                                 const float* __restrict__ Wh0,
                                                 const float* __restrict__ Wout,
                                                 const float* __restrict__ vxp,
                                                 const float* __restrict__ vyp,
                                                 float* __restrict__ out) {
    __shared__ float lw[H_DIM * H_DIM];                 // 64 KB, lw[swz_idx(h,i)]
    __shared__ float sf[8][64 * 32];                    // 64 KB, per-wave spike floats
    const int tid = threadIdx.x;
    for (int e = tid; e < H_DIM * H_DIM; e += 512) {
        const int i = e >> 7, h = e & 127;              // Wh0 flat = i*128 + h
        lw[swz_idx(h, i)] = Wh0[e];
    }
    __syncthreads();

    const int w = tid >> 6, lane = tid & 63;
    const int t  = blockIdx.y;
    const int i0 = lane << 1;
    float* sfw = sf[w];
    const int lbase = lane * 32;                        // this lane's publish strip
    const float wex = Wout[i0],     wey = Wout[H_DIM + i0];
    const float wox = Wout[i0 + 1], woy = Wout[H_DIM + i0 + 1];
    const float vx = vxp[0], vy = vyp[0];
    const int b0 = (blockIdx.x << 7) + (w << 4);        // 16 consecutive b per wave

    float m1a[16], m1b[16], m2a[16], m2b[16], poa[16], pob[16];
    float c1a[16], c1b[16];
    bool  s1a[16], s1b[16], s2a[16], s2b[16];
#pragma unroll
    for (int k = 0; k < 16; ++k) {
        m1a[k]=0.f; m1b[k]=0.f; m2a[k]=0.f; m2b[k]=0.f; poa[k]=0.f; pob[k]=0.f;
        s1a[k]=false; s1b[k]=false; s2a[k]=false; s2b[k]=false;
    }

    // load cur1 for s = 0
    {
        const int wi = widx_for(t, 0);
#pragma unroll
        for (int k = 0; k < 16; ++k) {
            c1a[k] = 0.f; c1b[k] = 0.f;
            if (wi >= 0) {
                const float2 v = *(const float2*)
                    &CUR1[((size_t)wi * BATCH + b0 + k) * H_DIM + i0];
                c1a[k] = v.x; c1b[k] = v.y;
            }
        }
    }

#pragma unroll 1
    for (int s = 0; s < 7; ++s) {
        // ---- mem1 update + spike floats (exact), publish to sf -------------
        float sev[16], sov[16];
#pragma unroll
        for (int k = 0; k < 16; ++k) {
            m1a[k] = s1a[k] ? 0.f : __fadd_rn(__fmul_rn(0.9f, m1a[k]), c1a[k]);
            m1b[k] = s1b[k] ? 0.f : __fadd_rn(__fmul_rn(0.9f, m1b[k]), c1b[k]);
            s1a[k] = m1a[k] > 0.5f; s1b[k] = m1b[k] > 0.5f;
            sev[k] = s1a[k] ? 1.0f : 0.0f;              // v_cndmask, once per step
            sov[k] = s1b[k] ? 1.0f : 0.0f;
        }
        // chunks 0..3 = se[0..15], 4..7 = so[0..15]; chunk swizzled by lane&7
#pragma unroll
        for (int c = 0; c < 4; ++c) {
            float4 v;
            v.x = sev[c*4]; v.y = sev[c*4+1]; v.z = sev[c*4+2]; v.w = sev[c*4+3];
            *(float4*)&sfw[lbase + ((c     ^ (lane & 7)) << 2)] = v;
            v.x = sov[c*4]; v.y = sov[c*4+1]; v.z = sov[c*4+2]; v.w = sov[c*4+3];
            *(float4*)&sfw[lbase + (((c+4) ^ (lane & 7)) << 2)] = v;
        }

        // ---- prefetch next step's cur1 into the now-dead c1 registers ------
        const int win = (s < 6) ? widx_for(t, s + 1) : -1;
#pragma unroll
        for (int k = 0; k < 16; ++k) {
            c1a[k] = 0.f; c1b[k] = 0.f;
            if (win >= 0) {
                const float2 v = *(const float2*)
                    &CUR1[((size_t)win * BATCH + b0 + k) * H_DIM + i0];
                c1a[k] = v.x; c1b[k] = v.y;
            }
        }

        // ---- dense cur2: ascending h, fma with broadcast spike floats ------
        float c2a[16], c2b[16];
#pragma unroll
        for (int k = 0; k < 16; ++k) { c2a[k] = 0.f; c2b[k] = 0.f; }
#pragma unroll 8
        for (int j = 0; j < 64; ++j) {
            const float2 we = *(const float2*)&lw[swz_idx(2*j,     i0)]; // per-lane b64
            const float2 wo = *(const float2*)&lw[swz_idx(2*j + 1, i0)];
            const int jb = j * 32, jx = (j & 7) << 2;                    // chunk swizzle
            const float4 e0 = *(const float4*)&sfw[jb + ((0  << 2) ^ jx)];
            const float4 e1 = *(const float4*)&sfw[jb + ((1  << 2) ^ jx)];
            const float4 e2 = *(const float4*)&sfw[jb + ((2  << 2) ^ jx)];
            const float4 e3 = *(const float4*)&sfw[jb + ((3  << 2) ^ jx)];
            const float4 o0 = *(const float4*)&sfw[jb + ((4  << 2) ^ jx)];
            const float4 o1 = *(const float4*)&sfw[jb + ((5  << 2) ^ jx)];
            const float4 o2 = *(const float4*)&sfw[jb + ((6  << 2) ^ jx)];
            const float4 o3 = *(const float4*)&sfw[jb + ((7  << 2) ^ jx)];
            const float se[16] = {e0.x,e0.y,e0.z,e0.w, e1.x,e1.y,e1.z,e1.w,
                                  e2.x,e2.y,e2.z,e2.w, e3.x,e3.y,e3.z,e3.w};
            const float so[16] = {o0.x,o0.y,o0.z,o0.w, o1.x,o1.y,o1.z,o1.w,
                                  o2.x,o2.y,o2.z,o2.w, o3.x,o3.y,o3.z,o3.w};
#pragma unroll
            for (int k = 0; k < 16; ++k) {
                c2a[k] = __fmaf_rn(se[k], we.x, c2a[k]);   // h = 2j
                c2b[k] = __fmaf_rn(se[k], we.y, c2b[k]);
                c2a[k] = __fmaf_rn(so[k], wo.x, c2a[k]);   // h = 2j+1
                c2b[k] = __fmaf_rn(so[k], wo.y, c2b[k]);
            }
        }

        // ---- mem2 + spikes (exact) and linear output tail (relaxed) --------
#pragma unroll
        for (int k = 0; k < 16; ++k) {
            m2a[k] = s2a[k] ? 0.f : __fadd_rn(__fmul_rn(0.9f, m2a[k]), c2a[k]);
            m2b[k] = s2b[k] ? 0.f : __fadd_rn(__fmul_rn(0.9f, m2b[k]), c2b[k]);
            s2a[k] = m2a[k] > 0.5f; s2b[k] = m2b[k] > 0.5f;
            const float p0 = (s2a[k] ? wex : 0.f) + (s2b[k] ? wox : 0.f);
            const float p1 = (s2a[k] ? wey : 0.f) + (s2b[k] ? woy : 0.f);
            poa[k] = __fmaf_rn(0.9f, poa[k], p0);       // mem_out is linear: order-safe
            pob[k] = __fmaf_rn(0.9f, pob[k], p1);
        }
    }

    // ---- reduce per-lane output partials, write -----------------------------
#pragma unroll
    for (int k = 0; k < 16; ++k) {
        float r0 = poa[k], r1 = pob[k];
#pragma unroll
        for (int off = 32; off > 0; off >>= 1) {
            r0 += __shfl_xor(r0, off);
            r1 += __shfl_xor(r1, off);
        }
        if (lane == 0) {
            float2 o;
            o.x = __fmul_rn(r0, vx);
            o.y = __fmul_rn(r1, vy);
            *(float2*)(out + ((size_t)t * BATCH + b0 + k) * 2) = o;
        }
    }
}

// ---------------------------------------------------------------------------
extern "C" void kernel_launch(void* const* d_in, const int* in_sizes, int n_in,
                              void* d_out, int out_size, void* d_ws, size_t ws_size,
                              hipStream_t stream) {
    const float* x    = (const float*)d_in[0];   // (128,1024,96)
    const float* Win  = (const float*)d_in[1];   // (128,96)
    const float* Wh0  = (const float*)d_in[2];   // (128,128)
    const float* Wout = (const float*)d_in[3];   // (2,128)
    const float* vx   = (const float*)d_in[4];   // (1,)
    const float* vy   = (const float*)d_in[5];   // (1,)
    float* out  = (float*)d_out;                 // (128,1024,2)
    float* CUR1 = (float*)d_ws;                  // 163*1024*128*4 = 85.5 MB

    kA_wincur<<<dim3(NWIN, BATCH / 32),    dim3(256), 0, stream>>>(x, Win, CUR1);
    kB_snn   <<<dim3(BATCH / 128, T_STEPS), dim3(512), 0, stream>>>(CUR1, Wh0, Wout, vx, vy, out);
}